// Round 1
// baseline (613.574 us; speedup 1.0000x reference)
//
#include <hip/hip_runtime.h>
#include <cstddef>

#define B_   16
#define N_   4096
#define S_   1024
#define D1_  64
#define D2_  256
#define CIN_ 320
#define H_   256

__device__ __forceinline__ float relu_f(float v) { return fmaxf(v, 0.0f); }

// ---------------------------------------------------------------------------
// Batched tiled transpose: in[z][R][C] -> out[z][C][R]
// ---------------------------------------------------------------------------
__global__ __launch_bounds__(256) void transpose_b(
    const float* __restrict__ in, float* __restrict__ out,
    int R, int C, size_t inStride, size_t outStride) {
  __shared__ float tile[32][33];
  in  += (size_t)blockIdx.z * inStride;
  out += (size_t)blockIdx.z * outStride;
  int c0 = blockIdx.x * 32, r0 = blockIdx.y * 32;
  int tx = threadIdx.x, ty = threadIdx.y;   // (32, 8)
#pragma unroll
  for (int j = 0; j < 4; ++j) {
    int r = r0 + ty + j * 8;
    tile[ty + j * 8][tx] = in[(size_t)r * C + c0 + tx];
  }
  __syncthreads();
#pragma unroll
  for (int j = 0; j < 4; ++j) {
    int c = c0 + ty + j * 8;
    out[(size_t)c * R + r0 + tx] = tile[tx][ty + j * 8];
  }
}

// ---------------------------------------------------------------------------
// 3-NN (smallest sq-distances, tie -> earlier index like top_k) + weights
// ---------------------------------------------------------------------------
__global__ __launch_bounds__(256) void knn3_kernel(
    const float* __restrict__ xyz1, const float* __restrict__ xyz2,
    int* __restrict__ idxo, float* __restrict__ wo) {
  __shared__ float X[S_], Y[S_], Z[S_], SQ[S_];
  int b = blockIdx.y;
  int n = blockIdx.x * 256 + threadIdx.x;
  const float* x2b = xyz2 + (size_t)b * 3 * S_;
  for (int i = threadIdx.x; i < S_; i += 256) {
    X[i] = x2b[i];
    Y[i] = x2b[S_ + i];
    Z[i] = x2b[2 * S_ + i];
  }
  __syncthreads();
  for (int i = threadIdx.x; i < S_; i += 256)
    SQ[i] = X[i] * X[i] + Y[i] * Y[i] + Z[i] * Z[i];
  __syncthreads();

  const float* x1b = xyz1 + (size_t)b * 3 * N_;
  float px = x1b[n], py = x1b[N_ + n], pz = x1b[2 * N_ + n];
  float sq1 = px * px + py * py + pz * pz;

  float d0 = 1e30f, d1 = 1e30f, d2 = 1e30f;
  int i0 = 0, i1 = 0, i2 = 0;
  for (int s = 0; s < S_; ++s) {
    float d = sq1 + SQ[s] - 2.0f * (px * X[s] + py * Y[s] + pz * Z[s]);
    if (d < d2) {
      if (d < d1) {
        if (d < d0) { d2 = d1; i2 = i1; d1 = d0; i1 = i0; d0 = d; i0 = s; }
        else        { d2 = d1; i2 = i1; d1 = d;  i1 = s; }
      } else        { d2 = d;  i2 = s; }
    }
  }
  float r0 = 1.0f / (d0 + 1e-8f);
  float r1 = 1.0f / (d1 + 1e-8f);
  float r2 = 1.0f / (d2 + 1e-8f);
  float rs = 1.0f / (r0 + r1 + r2);
  size_t base = ((size_t)b * N_ + n) * 3;
  idxo[base] = i0; idxo[base + 1] = i1; idxo[base + 2] = i2;
  wo[base] = r0 * rs; wo[base + 1] = r1 * rs; wo[base + 2] = r2 * rs;
}

// ---------------------------------------------------------------------------
// Build x = concat(points1, interp)  as [B][CIN][N]
// ---------------------------------------------------------------------------
__global__ __launch_bounds__(256) void build_xc(
    const float* __restrict__ points1, const float* __restrict__ p2t,
    const int* __restrict__ idxo, const float* __restrict__ wo,
    float* __restrict__ xc) {
  int b = blockIdx.y;
  int n = blockIdx.x * 256 + threadIdx.x;
  const float* p1b = points1 + (size_t)b * D1_ * N_;
  float* xcb = xc + (size_t)b * CIN_ * N_;
#pragma unroll 8
  for (int c = 0; c < D1_; ++c)
    xcb[(size_t)c * N_ + n] = p1b[(size_t)c * N_ + n];

  size_t base = ((size_t)b * N_ + n) * 3;
  int i0 = idxo[base], i1 = idxo[base + 1], i2 = idxo[base + 2];
  float w0 = wo[base], w1 = wo[base + 1], w2 = wo[base + 2];
  const float4* r0 = (const float4*)(p2t + ((size_t)b * S_ + i0) * D2_);
  const float4* r1 = (const float4*)(p2t + ((size_t)b * S_ + i1) * D2_);
  const float4* r2 = (const float4*)(p2t + ((size_t)b * S_ + i2) * D2_);
#pragma unroll 4
  for (int q = 0; q < D2_ / 4; ++q) {
    float4 a = r0[q], c4 = r1[q], e = r2[q];
    float v0 = w0 * a.x + w1 * c4.x + w2 * e.x;
    float v1 = w0 * a.y + w1 * c4.y + w2 * e.y;
    float v2 = w0 * a.z + w1 * c4.z + w2 * e.z;
    float v3 = w0 * a.w + w1 * c4.w + w2 * e.w;
    xcb[(size_t)(D1_ + 4 * q + 0) * N_ + n] = v0;
    xcb[(size_t)(D1_ + 4 * q + 1) * N_ + n] = v1;
    xcb[(size_t)(D1_ + 4 * q + 2) * N_ + n] = v2;
    xcb[(size_t)(D1_ + 4 * q + 3) * N_ + n] = v3;
  }
}

// ---------------------------------------------------------------------------
// Tiled fp32 GEMM: Y[b][m][n] = sum_k Wt[k][m] * f(X[b][k][n]) + bias[m]
// f = identity (TRANS=false) or BN+ReLU via per-k scale/shift (TRANS=true)
// Tile 64(m) x 64(n), BK=16, 256 threads, 4x4 micro-tile.
// ---------------------------------------------------------------------------
template <bool TRANS>
__global__ __launch_bounds__(256) void gemm_bn(
    const float* __restrict__ Wt,    // [K][H_]
    const float* __restrict__ X,     // [B][K][N_]
    const float* __restrict__ bias,  // [H_]
    const float* __restrict__ sc,    // [K] (TRANS only)
    const float* __restrict__ sh,    // [K] (TRANS only)
    float* __restrict__ Y,           // [B][H_][N_]
    int K) {
  __shared__ float As[16][64];
  __shared__ float Bs[16][64];
  int b  = blockIdx.z;
  int n0 = blockIdx.x * 64;
  int m0 = blockIdx.y * 64;
  int tid = threadIdx.x;
  int tx = tid & 15, ty = tid >> 4;
  const float* Xb = X + (size_t)b * K * N_;

  float acc[4][4] = {};
  for (int k0 = 0; k0 < K; k0 += 16) {
#pragma unroll
    for (int r = 0; r < 4; ++r) {
      int kk = (tid >> 6) + r * 4;
      int om = tid & 63;
      As[kk][om] = Wt[(size_t)(k0 + kk) * H_ + m0 + om];
    }
#pragma unroll
    for (int r = 0; r < 4; ++r) {
      int kk = (tid >> 6) + r * 4;
      int nn = tid & 63;
      float v = Xb[(size_t)(k0 + kk) * N_ + n0 + nn];
      if (TRANS) v = relu_f(v * sc[k0 + kk] + sh[k0 + kk]);
      Bs[kk][nn] = v;
    }
    __syncthreads();
#pragma unroll
    for (int kk = 0; kk < 16; ++kk) {
      float4 av = *(const float4*)&As[kk][ty * 4];
      float4 bv = *(const float4*)&Bs[kk][tx * 4];
      const float* ap = (const float*)&av;
#pragma unroll
      for (int j = 0; j < 4; ++j) {
        acc[j][0] += ap[j] * bv.x;
        acc[j][1] += ap[j] * bv.y;
        acc[j][2] += ap[j] * bv.z;
        acc[j][3] += ap[j] * bv.w;
      }
    }
    __syncthreads();
  }
#pragma unroll
  for (int j = 0; j < 4; ++j) {
    int m = m0 + ty * 4 + j;
    float bs = bias[m];
    float4 o;
    o.x = acc[j][0] + bs;
    o.y = acc[j][1] + bs;
    o.z = acc[j][2] + bs;
    o.w = acc[j][3] + bs;
    *(float4*)&Y[((size_t)b * H_ + m) * N_ + n0 + tx * 4] = o;
  }
}

// ---------------------------------------------------------------------------
// Per-channel BN stats over (B, N), folded to scale/shift. 1 block / channel.
// ---------------------------------------------------------------------------
__global__ __launch_bounds__(256) void bn_stats(
    const float* __restrict__ Yp, const float* __restrict__ gamma,
    const float* __restrict__ beta, float* __restrict__ sc,
    float* __restrict__ sh) {
  int c = blockIdx.x;
  float s1 = 0.f, s2 = 0.f;
  for (int b = 0; b < B_; ++b) {
    const float* p = Yp + ((size_t)b * H_ + c) * N_;
    for (int n = threadIdx.x; n < N_; n += 256) {
      float v = p[n];
      s1 += v;
      s2 += v * v;
    }
  }
  __shared__ float S1[256], S2[256];
  S1[threadIdx.x] = s1;
  S2[threadIdx.x] = s2;
  __syncthreads();
  for (int off = 128; off > 0; off >>= 1) {
    if (threadIdx.x < off) {
      S1[threadIdx.x] += S1[threadIdx.x + off];
      S2[threadIdx.x] += S2[threadIdx.x + off];
    }
    __syncthreads();
  }
  if (threadIdx.x == 0) {
    const float inv = 1.0f / (float)(B_ * N_);
    float mean = S1[0] * inv;
    float var  = S2[0] * inv - mean * mean;
    float rs   = rsqrtf(var + 1e-5f);
    float g    = gamma[c] * rs;
    sc[c] = g;
    sh[c] = beta[c] - mean * g;
  }
}

// ---------------------------------------------------------------------------
// In-place BN+ReLU on Y [B][H_][N_]
// ---------------------------------------------------------------------------
__global__ __launch_bounds__(256) void bn_apply(
    float* __restrict__ Yp, const float* __restrict__ sc,
    const float* __restrict__ sh) {
  const size_t total4 = (size_t)B_ * H_ * N_ / 4;
  for (size_t i = (size_t)blockIdx.x * blockDim.x + threadIdx.x; i < total4;
       i += (size_t)gridDim.x * blockDim.x) {
    float4 v = ((float4*)Yp)[i];
    int c = (int)(((i * 4) / N_) & (H_ - 1));
    float s = sc[c], t = sh[c];
    v.x = relu_f(v.x * s + t);
    v.y = relu_f(v.y * s + t);
    v.z = relu_f(v.z * s + t);
    v.w = relu_f(v.w * s + t);
    ((float4*)Yp)[i] = v;
  }
}

// ---------------------------------------------------------------------------
extern "C" void kernel_launch(void* const* d_in, const int* in_sizes, int n_in,
                              void* d_out, int out_size, void* d_ws,
                              size_t ws_size, hipStream_t stream) {
  const float* xyz1    = (const float*)d_in[0];
  const float* xyz2    = (const float*)d_in[1];
  const float* points1 = (const float*)d_in[2];
  const float* points2 = (const float*)d_in[3];
  const float* W1  = (const float*)d_in[4];
  const float* b1  = (const float*)d_in[5];
  const float* g1  = (const float*)d_in[6];
  const float* bt1 = (const float*)d_in[7];
  const float* W2  = (const float*)d_in[8];
  const float* b2  = (const float*)d_in[9];
  const float* g2  = (const float*)d_in[10];
  const float* bt2 = (const float*)d_in[11];
  float* out = (float*)d_out;
  float* ws  = (float*)d_ws;

  // workspace carve-up (floats)
  float* p2t = ws;                               // [B][S][D2]
  float* Wt1 = p2t + (size_t)B_ * S_ * D2_;      // [CIN][H]
  float* Wt2 = Wt1 + (size_t)CIN_ * H_;          // [H][H]
  int*   idxb = (int*)(Wt2 + (size_t)H_ * H_);   // [B][N][3]
  float* wb  = (float*)(idxb + (size_t)B_ * N_ * 3);  // [B][N][3]
  float* xc  = wb + (size_t)B_ * N_ * 3;         // [B][CIN][N]
  float* h1  = xc + (size_t)B_ * CIN_ * N_;      // [B][H][N]
  float* sc1 = h1 + (size_t)B_ * H_ * N_;
  float* sh1 = sc1 + H_;
  float* sc2 = sh1 + H_;
  float* sh2 = sc2 + H_;

  dim3 blk32(32, 8);

  // points2 [B][D2][S] -> p2t [B][S][D2]
  transpose_b<<<dim3(S_ / 32, D2_ / 32, B_), blk32, 0, stream>>>(
      points2, p2t, D2_, S_, (size_t)D2_ * S_, (size_t)S_ * D2_);
  // W1 [H][CIN] -> Wt1 [CIN][H]
  transpose_b<<<dim3(CIN_ / 32, H_ / 32, 1), blk32, 0, stream>>>(
      W1, Wt1, H_, CIN_, 0, 0);
  // W2 [H][H] -> Wt2 [H][H]
  transpose_b<<<dim3(H_ / 32, H_ / 32, 1), blk32, 0, stream>>>(
      W2, Wt2, H_, H_, 0, 0);

  knn3_kernel<<<dim3(N_ / 256, B_), 256, 0, stream>>>(xyz1, xyz2, idxb, wb);

  build_xc<<<dim3(N_ / 256, B_), 256, 0, stream>>>(points1, p2t, idxb, wb, xc);

  // layer 1: h1 = W1 @ x + b1 (pre-BN)
  gemm_bn<false><<<dim3(N_ / 64, H_ / 64, B_), 256, 0, stream>>>(
      Wt1, xc, b1, nullptr, nullptr, h1, CIN_);
  bn_stats<<<H_, 256, 0, stream>>>(h1, g1, bt1, sc1, sh1);

  // layer 2: h2 = W2 @ bnrelu(h1) + b2 (pre-BN) -> d_out
  gemm_bn<true><<<dim3(N_ / 64, H_ / 64, B_), 256, 0, stream>>>(
      Wt2, h1, b2, sc1, sh1, out, H_);
  bn_stats<<<H_, 256, 0, stream>>>(out, g2, bt2, sc2, sh2);

  // final BN+ReLU in place on d_out
  bn_apply<<<4096, 256, 0, stream>>>(out, sc2, sh2);
}

// Round 2
// 311.708 us; speedup vs baseline: 1.9684x; 1.9684x over previous
//
#include <hip/hip_runtime.h>
#include <cstddef>

#define B_   16
#define N_   4096
#define S_   1024
#define D1_  64
#define D2_  256
#define CIN_ 320
#define H_   256

using short8 = __attribute__((ext_vector_type(8))) short;
using f32x4  = __attribute__((ext_vector_type(4))) float;

__device__ __forceinline__ float relu_f(float v) { return fmaxf(v, 0.0f); }

__device__ __forceinline__ ushort f2bf(float f) {
  unsigned u = __builtin_bit_cast(unsigned, f);
  u += 0x7fffu + ((u >> 16) & 1u);   // round-to-nearest-even
  return (ushort)(u >> 16);
}

// ---------------------------------------------------------------------------
// Batched tiled transpose: in[z][R][C] -> out[z][C][R]   (fp32)
// ---------------------------------------------------------------------------
__global__ __launch_bounds__(256) void transpose_b(
    const float* __restrict__ in, float* __restrict__ out,
    int R, int C, size_t inStride, size_t outStride) {
  __shared__ float tile[32][33];
  in  += (size_t)blockIdx.z * inStride;
  out += (size_t)blockIdx.z * outStride;
  int c0 = blockIdx.x * 32, r0 = blockIdx.y * 32;
  int tx = threadIdx.x, ty = threadIdx.y;   // (32, 8)
#pragma unroll
  for (int j = 0; j < 4; ++j) {
    int r = r0 + ty + j * 8;
    tile[ty + j * 8][tx] = in[(size_t)r * C + c0 + tx];
  }
  __syncthreads();
#pragma unroll
  for (int j = 0; j < 4; ++j) {
    int c = c0 + ty + j * 8;
    out[(size_t)c * R + r0 + tx] = tile[tx][ty + j * 8];
  }
}

// ---------------------------------------------------------------------------
// fp32 -> bf16 elementwise
// ---------------------------------------------------------------------------
__global__ __launch_bounds__(256) void f2bf_kernel(
    const float* __restrict__ in, ushort* __restrict__ out, int n) {
  int i = blockIdx.x * 256 + threadIdx.x;
  if (i < n) out[i] = f2bf(in[i]);
}

// ---------------------------------------------------------------------------
// 3-NN (smallest sq-distances, tie -> earlier index) + inverse-dist weights
// ---------------------------------------------------------------------------
__global__ __launch_bounds__(256) void knn3_kernel(
    const float* __restrict__ xyz1, const float* __restrict__ xyz2,
    int* __restrict__ idxo, float* __restrict__ wo) {
  __shared__ float X[S_], Y[S_], Z[S_], SQ[S_];
  int b = blockIdx.y;
  int n = blockIdx.x * 256 + threadIdx.x;
  const float* x2b = xyz2 + (size_t)b * 3 * S_;
  for (int i = threadIdx.x; i < S_; i += 256) {
    X[i] = x2b[i];
    Y[i] = x2b[S_ + i];
    Z[i] = x2b[2 * S_ + i];
  }
  __syncthreads();
  for (int i = threadIdx.x; i < S_; i += 256)
    SQ[i] = X[i] * X[i] + Y[i] * Y[i] + Z[i] * Z[i];
  __syncthreads();

  const float* x1b = xyz1 + (size_t)b * 3 * N_;
  float px = x1b[n], py = x1b[N_ + n], pz = x1b[2 * N_ + n];
  float sq1 = px * px + py * py + pz * pz;

  float d0 = 1e30f, d1 = 1e30f, d2 = 1e30f;
  int i0 = 0, i1 = 0, i2 = 0;
  for (int s = 0; s < S_; ++s) {
    float d = sq1 + SQ[s] - 2.0f * (px * X[s] + py * Y[s] + pz * Z[s]);
    if (d < d2) {
      if (d < d1) {
        if (d < d0) { d2 = d1; i2 = i1; d1 = d0; i1 = i0; d0 = d; i0 = s; }
        else        { d2 = d1; i2 = i1; d1 = d;  i1 = s; }
      } else        { d2 = d;  i2 = s; }
    }
  }
  float r0 = 1.0f / (d0 + 1e-8f);
  float r1 = 1.0f / (d1 + 1e-8f);
  float r2 = 1.0f / (d2 + 1e-8f);
  float rs = 1.0f / (r0 + r1 + r2);
  size_t base = ((size_t)b * N_ + n) * 3;
  idxo[base] = i0; idxo[base + 1] = i1; idxo[base + 2] = i2;
  wo[base] = r0 * rs; wo[base + 1] = r1 * rs; wo[base + 2] = r2 * rs;
}

// ---------------------------------------------------------------------------
// Build xt[b][n][320] (bf16, k-contiguous) = concat(points1^T, interp)
// 4 threads per point, 80 channels each.
// ---------------------------------------------------------------------------
__global__ __launch_bounds__(256) void build_xct(
    const float* __restrict__ p1t,   // [B][N][64]
    const float* __restrict__ p2t,   // [B][S][256]
    const int* __restrict__ idxo, const float* __restrict__ wo,
    ushort* __restrict__ xt) {
  int b = blockIdx.y;
  int p = blockIdx.x * 64 + (threadIdx.x >> 2);
  int tq = threadIdx.x & 3;
  size_t pb = (size_t)b * N_ + p;
  size_t base3 = pb * 3;
  int i0 = idxo[base3], i1 = idxo[base3 + 1], i2 = idxo[base3 + 2];
  float w0 = wo[base3], w1 = wo[base3 + 1], w2 = wo[base3 + 2];
  const float4* R0 = (const float4*)(p2t + ((size_t)b * S_ + i0) * D2_);
  const float4* R1 = (const float4*)(p2t + ((size_t)b * S_ + i1) * D2_);
  const float4* R2 = (const float4*)(p2t + ((size_t)b * S_ + i2) * D2_);
  ushort* o = xt + pb * CIN_ + tq * 80;

  if (tq == 0) {
    const float4* P1 = (const float4*)(p1t + pb * D1_);
#pragma unroll
    for (int q = 0; q < 16; ++q) {
      float4 v = P1[q];
      ushort4 u; u.x = f2bf(v.x); u.y = f2bf(v.y); u.z = f2bf(v.z); u.w = f2bf(v.w);
      *(ushort4*)(o + q * 4) = u;
    }
#pragma unroll
    for (int q = 0; q < 4; ++q) {
      float4 a = R0[q], c = R1[q], e = R2[q];
      ushort4 u;
      u.x = f2bf(w0 * a.x + w1 * c.x + w2 * e.x);
      u.y = f2bf(w0 * a.y + w1 * c.y + w2 * e.y);
      u.z = f2bf(w0 * a.z + w1 * c.z + w2 * e.z);
      u.w = f2bf(w0 * a.w + w1 * c.w + w2 * e.w);
      *(ushort4*)(o + 64 + q * 4) = u;
    }
  } else {
    int cq = (tq * 80 - 64) >> 2;  // 4, 24, 44
#pragma unroll
    for (int q = 0; q < 20; ++q) {
      float4 a = R0[cq + q], c = R1[cq + q], e = R2[cq + q];
      ushort4 u;
      u.x = f2bf(w0 * a.x + w1 * c.x + w2 * e.x);
      u.y = f2bf(w0 * a.y + w1 * c.y + w2 * e.y);
      u.z = f2bf(w0 * a.z + w1 * c.z + w2 * e.z);
      u.w = f2bf(w0 * a.w + w1 * c.w + w2 * e.w);
      *(ushort4*)(o + q * 4) = u;
    }
  }
}

// ---------------------------------------------------------------------------
// MFMA GEMM: Y[b][m][n] = sum_k Wb[m][k] * Xt[b][n][k] + bias[m]
// A = Wb [256][K] bf16 (k-contig), B = Xt [B][4096][K] bf16 (k-contig)
// 128x128 tile, BK=64, 4 waves, wave tile 64x64 (4x4 16x16x32 frags).
// ---------------------------------------------------------------------------
template <int K>
__global__ __launch_bounds__(256) void gemm_mfma(
    const ushort* __restrict__ Wb, const ushort* __restrict__ Xt,
    const float* __restrict__ bias, float* __restrict__ Y) {
  constexpr int BK = 64, PAD = 72;
  __shared__ ushort Al[128][PAD];
  __shared__ ushort Bl[128][PAD];
  int b = blockIdx.z;
  int n0 = blockIdx.x * 128;
  int m0 = blockIdx.y * 128;
  int tid = threadIdx.x;
  int lane = tid & 63, wid = tid >> 6;
  int wm = (wid >> 1) * 64, wn = (wid & 1) * 64;
  int lr = lane & 15, lk = (lane >> 4) * 8;

  const ushort* Ag = Wb + (size_t)m0 * K;
  const ushort* Bg = Xt + ((size_t)b * N_ + n0) * K;

  f32x4 acc[4][4] = {};

  for (int k0 = 0; k0 < K; k0 += BK) {
    __syncthreads();
#pragma unroll
    for (int r = 0; r < 4; ++r) {
      int id = tid + r * 256;       // 0..1023
      int row = id >> 3;            // 0..127
      int ko = (id & 7) * 8;        // bf16 elements
      *(short8*)&Al[row][ko] = *(const short8*)&Ag[(size_t)row * K + k0 + ko];
      *(short8*)&Bl[row][ko] = *(const short8*)&Bg[(size_t)row * K + k0 + ko];
    }
    __syncthreads();
#pragma unroll
    for (int ks = 0; ks < 2; ++ks) {
      short8 af[4], bv[4];
#pragma unroll
      for (int i = 0; i < 4; ++i) {
        af[i] = *(const short8*)&Al[wm + i * 16 + lr][ks * 32 + lk];
        bv[i] = *(const short8*)&Bl[wn + i * 16 + lr][ks * 32 + lk];
      }
#pragma unroll
      for (int mf = 0; mf < 4; ++mf)
#pragma unroll
        for (int nf = 0; nf < 4; ++nf)
          acc[mf][nf] = __builtin_amdgcn_mfma_f32_16x16x32_bf16(
              af[mf], bv[nf], acc[mf][nf], 0, 0, 0);
    }
  }

#pragma unroll
  for (int mf = 0; mf < 4; ++mf) {
#pragma unroll
    for (int j = 0; j < 4; ++j) {
      int m = m0 + wm + mf * 16 + (lane >> 4) * 4 + j;
      float bvv = bias[m];
      float* yr = Y + ((size_t)b * H_ + m) * N_ + n0 + wn + lr;
#pragma unroll
      for (int nf = 0; nf < 4; ++nf)
        yr[nf * 16] = acc[mf][nf][j] + bvv;
    }
  }
}

// ---------------------------------------------------------------------------
// BN stats: per-(channel, batch) partial sums, then fold to scale/shift
// ---------------------------------------------------------------------------
__global__ __launch_bounds__(256) void bn_stats_part(
    const float* __restrict__ Yp, float* __restrict__ ps,
    float* __restrict__ ps2) {
  int c = blockIdx.x, b = blockIdx.y;
  const float4* p = (const float4*)(Yp + ((size_t)b * H_ + c) * N_);
  float s1 = 0.f, s2 = 0.f;
  for (int q = threadIdx.x; q < N_ / 4; q += 256) {
    float4 v = p[q];
    s1 += v.x + v.y + v.z + v.w;
    s2 += v.x * v.x + v.y * v.y + v.z * v.z + v.w * v.w;
  }
  __shared__ float S1[256], S2[256];
  S1[threadIdx.x] = s1; S2[threadIdx.x] = s2;
  __syncthreads();
  for (int off = 128; off > 0; off >>= 1) {
    if (threadIdx.x < off) {
      S1[threadIdx.x] += S1[threadIdx.x + off];
      S2[threadIdx.x] += S2[threadIdx.x + off];
    }
    __syncthreads();
  }
  if (threadIdx.x == 0) { ps[c * B_ + b] = S1[0]; ps2[c * B_ + b] = S2[0]; }
}

__global__ __launch_bounds__(256) void bn_stats_fin(
    const float* __restrict__ ps, const float* __restrict__ ps2,
    const float* __restrict__ gamma, const float* __restrict__ beta,
    float* __restrict__ sc, float* __restrict__ sh) {
  int c = threadIdx.x;
  float s1 = 0.f, s2 = 0.f;
  for (int b = 0; b < B_; ++b) { s1 += ps[c * B_ + b]; s2 += ps2[c * B_ + b]; }
  const float inv = 1.0f / (float)(B_ * N_);
  float mean = s1 * inv;
  float var  = s2 * inv - mean * mean;
  float g    = gamma[c] * rsqrtf(var + 1e-5f);
  sc[c] = g;
  sh[c] = beta[c] - mean * g;
}

// ---------------------------------------------------------------------------
// BN+ReLU + transpose: h1 [b][m][n] fp32 -> h1t [b][n][m] bf16
// ---------------------------------------------------------------------------
__global__ __launch_bounds__(256) void bnrelu_t(
    const float* __restrict__ Yp, const float* __restrict__ sc,
    const float* __restrict__ sh, ushort* __restrict__ Xt) {
  __shared__ float tile[32][33];
  int b = blockIdx.z;
  int n0 = blockIdx.x * 32, m0 = blockIdx.y * 32;
  int tx = threadIdx.x, ty = threadIdx.y;  // (32,8)
  const float* Yb = Yp + ((size_t)b * H_ + m0) * N_;
#pragma unroll
  for (int j = 0; j < 4; ++j) {
    int m = ty + j * 8;
    float v = Yb[(size_t)m * N_ + n0 + tx];
    tile[m][tx] = relu_f(v * sc[m0 + m] + sh[m0 + m]);
  }
  __syncthreads();
#pragma unroll
  for (int j = 0; j < 4; ++j) {
    int n = ty + j * 8;
    Xt[((size_t)b * N_ + n0 + n) * H_ + m0 + tx] = f2bf(tile[tx][n]);
  }
}

// ---------------------------------------------------------------------------
// In-place BN+ReLU on Y [B][H_][N_]
// ---------------------------------------------------------------------------
__global__ __launch_bounds__(256) void bn_apply(
    float* __restrict__ Yp, const float* __restrict__ sc,
    const float* __restrict__ sh) {
  const size_t total4 = (size_t)B_ * H_ * N_ / 4;
  for (size_t i = (size_t)blockIdx.x * blockDim.x + threadIdx.x; i < total4;
       i += (size_t)gridDim.x * blockDim.x) {
    float4 v = ((float4*)Yp)[i];
    int c = (int)(((i * 4) / N_) & (H_ - 1));
    float s = sc[c], t = sh[c];
    v.x = relu_f(v.x * s + t);
    v.y = relu_f(v.y * s + t);
    v.z = relu_f(v.z * s + t);
    v.w = relu_f(v.w * s + t);
    ((float4*)Yp)[i] = v;
  }
}

// ---------------------------------------------------------------------------
extern "C" void kernel_launch(void* const* d_in, const int* in_sizes, int n_in,
                              void* d_out, int out_size, void* d_ws,
                              size_t ws_size, hipStream_t stream) {
  const float* xyz1    = (const float*)d_in[0];
  const float* xyz2    = (const float*)d_in[1];
  const float* points1 = (const float*)d_in[2];
  const float* points2 = (const float*)d_in[3];
  const float* W1  = (const float*)d_in[4];
  const float* b1  = (const float*)d_in[5];
  const float* g1  = (const float*)d_in[6];
  const float* bt1 = (const float*)d_in[7];
  const float* W2  = (const float*)d_in[8];
  const float* b2  = (const float*)d_in[9];
  const float* g2  = (const float*)d_in[10];
  const float* bt2 = (const float*)d_in[11];
  float* out = (float*)d_out;
  float* ws  = (float*)d_ws;

  // workspace carve-up (float units)
  float* p2t = ws;                                    // [B][S][256] fp32
  float* p1t = p2t + (size_t)B_ * S_ * D2_;           // [B][N][64] fp32
  int*   idxb = (int*)(p1t + (size_t)B_ * N_ * D1_);  // [B][N][3]
  float* wb   = (float*)(idxb + (size_t)B_ * N_ * 3); // [B][N][3]
  ushort* W1b = (ushort*)(wb + (size_t)B_ * N_ * 3);  // [256][320] bf16
  ushort* W2b = W1b + (size_t)H_ * CIN_;              // [256][256] bf16
  float* after_w = (float*)(W2b + (size_t)H_ * H_);
  ushort* xct = (ushort*)after_w;                     // [B][N][320] bf16 (reused as h1t)
  float* h1 = (float*)(xct + (size_t)B_ * N_ * CIN_); // [B][256][N] fp32
  float* ps1  = h1 + (size_t)B_ * H_ * N_;            // [256][16]
  float* ps2  = ps1 + H_ * B_;
  float* sc1  = ps2 + H_ * B_;
  float* sh1  = sc1 + H_;
  float* sc2  = sh1 + H_;
  float* sh2  = sc2 + H_;
  ushort* h1t = xct;                                  // [B][N][256] bf16 (overlay)

  dim3 blk32(32, 8);

  f2bf_kernel<<<(H_ * CIN_ + 255) / 256, 256, 0, stream>>>(W1, W1b, H_ * CIN_);
  f2bf_kernel<<<(H_ * H_ + 255) / 256, 256, 0, stream>>>(W2, W2b, H_ * H_);

  // points2 [B][256][S] -> p2t [B][S][256]
  transpose_b<<<dim3(S_ / 32, D2_ / 32, B_), blk32, 0, stream>>>(
      points2, p2t, D2_, S_, (size_t)D2_ * S_, (size_t)S_ * D2_);
  // points1 [B][64][N] -> p1t [B][N][64]
  transpose_b<<<dim3(N_ / 32, D1_ / 32, B_), blk32, 0, stream>>>(
      points1, p1t, D1_, N_, (size_t)D1_ * N_, (size_t)N_ * D1_);

  knn3_kernel<<<dim3(N_ / 256, B_), 256, 0, stream>>>(xyz1, xyz2, idxb, wb);

  build_xct<<<dim3(N_ / 64, B_), 256, 0, stream>>>(p1t, p2t, idxb, wb, xct);

  // layer 1: h1 = W1 @ x + b1 (pre-BN)
  gemm_mfma<CIN_><<<dim3(N_ / 128, H_ / 128, B_), 256, 0, stream>>>(
      W1b, xct, b1, h1);
  bn_stats_part<<<dim3(H_, B_), 256, 0, stream>>>(h1, ps1, ps2);
  bn_stats_fin<<<1, 256, 0, stream>>>(ps1, ps2, g1, bt1, sc1, sh1);

  // bnrelu + transpose -> h1t bf16 [b][n][256]
  bnrelu_t<<<dim3(N_ / 32, H_ / 32, B_), blk32, 0, stream>>>(h1, sc1, sh1, h1t);

  // layer 2: out = W2 @ h1t + b2 (pre-BN)
  gemm_mfma<H_><<<dim3(N_ / 128, H_ / 128, B_), 256, 0, stream>>>(
      W2b, h1t, b2, out);
  bn_stats_part<<<dim3(H_, B_), 256, 0, stream>>>(out, ps1, ps2);
  bn_stats_fin<<<1, 256, 0, stream>>>(ps1, ps2, g2, bt2, sc2, sh2);

  bn_apply<<<4096, 256, 0, stream>>>(out, sc2, sh2);
}

// Round 3
// 279.953 us; speedup vs baseline: 2.1917x; 1.1134x over previous
//
#include <hip/hip_runtime.h>
#include <cstddef>

#define B_   16
#define N_   4096
#define S_   1024
#define D1_  64
#define D2_  256
#define CIN_ 320
#define H_   256
#define CH_  8
#define SC_  (S_ / CH_)          // 128 source points per chunk
#define P_   (B_ * (N_ / 128))   // 512 BN partials per channel

using short8 = __attribute__((ext_vector_type(8))) short;
using f32x4  = __attribute__((ext_vector_type(4))) float;

__device__ __forceinline__ float relu_f(float v) { return fmaxf(v, 0.0f); }

__device__ __forceinline__ ushort f2bf(float f) {
  unsigned u = __builtin_bit_cast(unsigned, f);
  u += 0x7fffu + ((u >> 16) & 1u);   // round-to-nearest-even
  return (ushort)(u >> 16);
}
__device__ __forceinline__ float bf2f(ushort u) {
  return __builtin_bit_cast(float, (unsigned)u << 16);
}

// ---------------------------------------------------------------------------
// Batched tiled transpose fp32 -> bf16: in[z][R][C] -> out[z][C][R]
// ---------------------------------------------------------------------------
__global__ __launch_bounds__(256) void transpose_bf(
    const float* __restrict__ in, ushort* __restrict__ out,
    int R, int C, size_t inStride, size_t outStride) {
  __shared__ float tile[32][33];
  in  += (size_t)blockIdx.z * inStride;
  out += (size_t)blockIdx.z * outStride;
  int c0 = blockIdx.x * 32, r0 = blockIdx.y * 32;
  int tx = threadIdx.x, ty = threadIdx.y;   // (32, 8)
#pragma unroll
  for (int j = 0; j < 4; ++j) {
    int r = r0 + ty + j * 8;
    tile[ty + j * 8][tx] = in[(size_t)r * C + c0 + tx];
  }
  __syncthreads();
#pragma unroll
  for (int j = 0; j < 4; ++j) {
    int c = c0 + ty + j * 8;
    out[(size_t)c * R + r0 + tx] = f2bf(tile[tx][ty + j * 8]);
  }
}

// ---------------------------------------------------------------------------
// fp32 -> bf16 elementwise (weights)
// ---------------------------------------------------------------------------
__global__ __launch_bounds__(256) void f2bf_kernel(
    const float* __restrict__ in, ushort* __restrict__ out, int n) {
  int i = blockIdx.x * 256 + threadIdx.x;
  if (i < n) out[i] = f2bf(in[i]);
}

// ---------------------------------------------------------------------------
// Chunked 3-NN: each block handles 256 query points x one 128-point chunk.
// Emits per-chunk top-3 (dist, global idx), sorted asc, ties -> lower idx.
// ---------------------------------------------------------------------------
__global__ __launch_bounds__(256) void knn3_part(
    const float* __restrict__ xyz1, const float* __restrict__ xyz2,
    float* __restrict__ pd, int* __restrict__ pi) {
  __shared__ float X[SC_], Y[SC_], Z[SC_], SQ[SC_];
  int b = blockIdx.z, ch = blockIdx.y;
  int n = blockIdx.x * 256 + threadIdx.x;
  const float* x2b = xyz2 + (size_t)b * 3 * S_ + ch * SC_;
  for (int i = threadIdx.x; i < SC_; i += 256) {
    float x = x2b[i], y = x2b[S_ + i], z = x2b[2 * S_ + i];
    X[i] = x; Y[i] = y; Z[i] = z;
    SQ[i] = x * x + y * y + z * z;
  }
  __syncthreads();

  const float* x1b = xyz1 + (size_t)b * 3 * N_;
  float px = x1b[n], py = x1b[N_ + n], pz = x1b[2 * N_ + n];
  float sq1 = px * px + py * py + pz * pz;

  float d0 = 1e30f, d1 = 1e30f, d2 = 1e30f;
  int i0 = 0, i1 = 0, i2 = 0;
#pragma unroll 4
  for (int s = 0; s < SC_; ++s) {
    float d = sq1 + SQ[s] - 2.0f * (px * X[s] + py * Y[s] + pz * Z[s]);
    int gi = ch * SC_ + s;
    if (d < d2) {
      if (d < d1) {
        if (d < d0) { d2 = d1; i2 = i1; d1 = d0; i1 = i0; d0 = d; i0 = gi; }
        else        { d2 = d1; i2 = i1; d1 = d;  i1 = gi; }
      } else        { d2 = d;  i2 = gi; }
    }
  }
  size_t base = (((size_t)b * N_ + n) * CH_ + ch) * 3;
  pd[base] = d0; pd[base + 1] = d1; pd[base + 2] = d2;
  pi[base] = i0; pi[base + 1] = i1; pi[base + 2] = i2;
}

// ---------------------------------------------------------------------------
// Merge 8 chunks' candidates (in chunk order = ascending idx) -> final 3-NN
// + inverse-distance weights.
// ---------------------------------------------------------------------------
__global__ __launch_bounds__(256) void knn3_merge(
    const float* __restrict__ pd, const int* __restrict__ pi,
    int* __restrict__ idxo, float* __restrict__ wo) {
  int g = blockIdx.x * 256 + threadIdx.x;   // b*N + n
  const float* p = pd + (size_t)g * CH_ * 3;
  const int*   q = pi + (size_t)g * CH_ * 3;
  float d0 = 1e30f, d1 = 1e30f, d2 = 1e30f;
  int i0 = 0, i1 = 0, i2 = 0;
#pragma unroll
  for (int t = 0; t < CH_ * 3; ++t) {
    float d = p[t];
    int gi = q[t];
    if (d < d2) {
      if (d < d1) {
        if (d < d0) { d2 = d1; i2 = i1; d1 = d0; i1 = i0; d0 = d; i0 = gi; }
        else        { d2 = d1; i2 = i1; d1 = d;  i1 = gi; }
      } else        { d2 = d;  i2 = gi; }
    }
  }
  float r0 = 1.0f / (d0 + 1e-8f);
  float r1 = 1.0f / (d1 + 1e-8f);
  float r2 = 1.0f / (d2 + 1e-8f);
  float rs = 1.0f / (r0 + r1 + r2);
  size_t base = (size_t)g * 3;
  idxo[base] = i0; idxo[base + 1] = i1; idxo[base + 2] = i2;
  wo[base] = r0 * rs; wo[base + 1] = r1 * rs; wo[base + 2] = r2 * rs;
}

// ---------------------------------------------------------------------------
// Build xt[b][n][320] bf16 (k-contig) = concat(points1^T, interp(points2^T))
// 4 threads per point, 80 channels each; bf16 sources.
// ---------------------------------------------------------------------------
__global__ __launch_bounds__(256) void build_xct(
    const ushort* __restrict__ p1tb,   // [B][N][64] bf16
    const ushort* __restrict__ p2tb,   // [B][S][256] bf16
    const int* __restrict__ idxo, const float* __restrict__ wo,
    ushort* __restrict__ xt) {
  int b = blockIdx.y;
  int p = blockIdx.x * 64 + (threadIdx.x >> 2);
  int tq = threadIdx.x & 3;
  size_t pb = (size_t)b * N_ + p;
  size_t base3 = pb * 3;
  int i0 = idxo[base3], i1 = idxo[base3 + 1], i2 = idxo[base3 + 2];
  float w0 = wo[base3], w1 = wo[base3 + 1], w2 = wo[base3 + 2];
  const ushort* R0 = p2tb + ((size_t)b * S_ + i0) * D2_;
  const ushort* R1 = p2tb + ((size_t)b * S_ + i1) * D2_;
  const ushort* R2 = p2tb + ((size_t)b * S_ + i2) * D2_;
  ushort* o = xt + pb * CIN_ + tq * 80;

  auto interp8 = [&](int c) {
    short8 a = *(const short8*)&R0[c];
    short8 d = *(const short8*)&R1[c];
    short8 e = *(const short8*)&R2[c];
    short8 r;
#pragma unroll
    for (int t = 0; t < 8; ++t) {
      float v = w0 * bf2f((ushort)a[t]) + w1 * bf2f((ushort)d[t]) +
                w2 * bf2f((ushort)e[t]);
      r[t] = (short)f2bf(v);
    }
    return r;
  };

  if (tq == 0) {
    const short8* P1 = (const short8*)(p1tb + pb * D1_);
#pragma unroll
    for (int q = 0; q < 8; ++q) *(short8*)(o + q * 8) = P1[q];
    *(short8*)(o + 64) = interp8(0);
    *(short8*)(o + 72) = interp8(8);
  } else {
    int cb = tq * 80 - 64;   // 16, 96, 176
#pragma unroll
    for (int q = 0; q < 10; ++q)
      *(short8*)(o + q * 8) = interp8(cb + q * 8);
  }
}

// ---------------------------------------------------------------------------
// MFMA GEMM + fused BN-stats epilogue.
//   A = Wb[H_][K] bf16 (k-contig), B = Xt[b][n][K] bf16 (k-contig)
//   BNIN: apply y = relu(x*scin[k]+shin[k]) to B during LDS staging.
//   Output: Yt[b][n][H_] bf16 (pre-BN, +bias)  [= next layer's B operand]
//   ps1/ps2: per-channel partial sums of y and y^2 over this block's n-range,
//            layout [P_][H_] (pidx = b*gridDim.x + blockIdx.x).
// 128x128 tile, BK=64, 4 waves, 4x4 16x16x32 frags per wave.
// ---------------------------------------------------------------------------
template <int K, bool BNIN>
__global__ __launch_bounds__(256) void gemm_fused(
    const ushort* __restrict__ Wb, const ushort* __restrict__ Xt,
    const float* __restrict__ bias, const float* __restrict__ scin,
    const float* __restrict__ shin, ushort* __restrict__ Yt,
    float* __restrict__ ps1, float* __restrict__ ps2) {
  constexpr int BK = 64, PAD = 72;
  __shared__ union {
    struct { ushort Al[128][PAD]; ushort Bl[128][PAD]; } st;
    struct { float S1[128][32]; float S2[128][32]; } rd;
  } sm;
  int b  = blockIdx.z;
  int n0 = blockIdx.x * 128;
  int m0 = blockIdx.y * 128;
  int tid = threadIdx.x;
  int lane = tid & 63, wid = tid >> 6;
  int wm = (wid >> 1) * 64, wn = (wid & 1) * 64;
  int lr = lane & 15, hi = lane >> 4, lk = hi * 8;

  const ushort* Ag = Wb + (size_t)m0 * K;
  const ushort* Bg = Xt + ((size_t)b * N_ + n0) * K;

  f32x4 acc[4][4] = {};

  for (int k0 = 0; k0 < K; k0 += BK) {
    __syncthreads();
#pragma unroll
    for (int r = 0; r < 4; ++r) {
      int id = tid + r * 256;       // 0..1023
      int row = id >> 3;            // 0..127
      int ko = (id & 7) * 8;        // bf16 element offset within BK
      *(short8*)&sm.st.Al[row][ko] =
          *(const short8*)&Ag[(size_t)row * K + k0 + ko];
      short8 raw = *(const short8*)&Bg[(size_t)row * K + k0 + ko];
      if (BNIN) {
        short8 pk;
#pragma unroll
        for (int e = 0; e < 8; ++e) {
          float x = bf2f((ushort)raw[e]);
          float y = relu_f(x * scin[k0 + ko + e] + shin[k0 + ko + e]);
          pk[e] = (short)f2bf(y);
        }
        raw = pk;
      }
      *(short8*)&sm.st.Bl[row][ko] = raw;
    }
    __syncthreads();
#pragma unroll
    for (int ks = 0; ks < 2; ++ks) {
      short8 af[4], bv[4];
#pragma unroll
      for (int i = 0; i < 4; ++i) {
        af[i] = *(const short8*)&sm.st.Al[wm + i * 16 + lr][ks * 32 + lk];
        bv[i] = *(const short8*)&sm.st.Bl[wn + i * 16 + lr][ks * 32 + lk];
      }
#pragma unroll
      for (int mf = 0; mf < 4; ++mf)
#pragma unroll
        for (int nf = 0; nf < 4; ++nf)
          acc[mf][nf] = __builtin_amdgcn_mfma_f32_16x16x32_bf16(
              af[mf], bv[nf], acc[mf][nf], 0, 0, 0);
    }
  }

  __syncthreads();   // done with staging LDS; reuse as reduction scratch

  float sum1[4][4] = {}, sum2[4][4] = {};
#pragma unroll
  for (int mf = 0; mf < 4; ++mf) {
#pragma unroll
    for (int nf = 0; nf < 4; ++nf) {
      int n = n0 + wn + nf * 16 + lr;
      ushort4 u;
#pragma unroll
      for (int j = 0; j < 4; ++j) {
        float v = acc[mf][nf][j] + bias[m0 + wm + mf * 16 + hi * 4 + j];
        sum1[mf][j] += v;
        sum2[mf][j] += v * v;
        ((ushort*)&u)[j] = f2bf(v);
      }
      *(ushort4*)&Yt[((size_t)b * N_ + n) * H_ + m0 + wm + mf * 16 + hi * 4] = u;
    }
  }
  int col = (wid & 1) * 16 + lr;
#pragma unroll
  for (int mf = 0; mf < 4; ++mf)
#pragma unroll
    for (int j = 0; j < 4; ++j) {
      int c = wm + mf * 16 + hi * 4 + j;
      sm.rd.S1[c][col] = sum1[mf][j];
      sm.rd.S2[c][col] = sum2[mf][j];
    }
  __syncthreads();
  int pidx = b * gridDim.x + blockIdx.x;
  int c = tid & 127;
  float s = 0.f;
  if (tid < 128) {
#pragma unroll
    for (int k = 0; k < 32; ++k) s += sm.rd.S1[c][k];
    ps1[(size_t)pidx * H_ + m0 + c] = s;
  } else {
#pragma unroll
    for (int k = 0; k < 32; ++k) s += sm.rd.S2[c][k];
    ps2[(size_t)pidx * H_ + m0 + c] = s;
  }
}

// ---------------------------------------------------------------------------
// Reduce P_ partials per channel -> BN scale/shift
// ---------------------------------------------------------------------------
__global__ __launch_bounds__(256) void bn_stats_fin(
    const float* __restrict__ ps1, const float* __restrict__ ps2,
    const float* __restrict__ gamma, const float* __restrict__ beta,
    float* __restrict__ sc, float* __restrict__ sh) {
  int c = threadIdx.x;
  float s1 = 0.f, s2 = 0.f;
  for (int k = 0; k < P_; ++k) {
    s1 += ps1[(size_t)k * H_ + c];
    s2 += ps2[(size_t)k * H_ + c];
  }
  const float inv = 1.0f / (float)(B_ * N_);
  float mean = s1 * inv;
  float var  = s2 * inv - mean * mean;
  float g    = gamma[c] * rsqrtf(var + 1e-5f);
  sc[c] = g;
  sh[c] = beta[c] - mean * g;
}

// ---------------------------------------------------------------------------
// Final: h2b[b][n][m] bf16 (pre-BN) -> BN+ReLU -> d_out[b][m][n] fp32
// ---------------------------------------------------------------------------
__global__ __launch_bounds__(256) void bn_out_t(
    const ushort* __restrict__ Hb, const float* __restrict__ sc,
    const float* __restrict__ sh, float* __restrict__ out) {
  __shared__ float tile[32][33];   // [m][n]
  int b = blockIdx.z;
  int n0 = blockIdx.x * 32, m0 = blockIdx.y * 32;
  int tx = threadIdx.x, ty = threadIdx.y;   // (32,8)
  float scv = sc[m0 + tx], shv = sh[m0 + tx];
#pragma unroll
  for (int j = 0; j < 4; ++j) {
    int n = n0 + ty + j * 8;
    float x = bf2f(Hb[((size_t)b * N_ + n) * H_ + m0 + tx]);
    tile[tx][ty + j * 8] = relu_f(x * scv + shv);
  }
  __syncthreads();
#pragma unroll
  for (int j = 0; j < 4; ++j) {
    int m = ty + j * 8;
    out[((size_t)b * H_ + m0 + m) * N_ + n0 + tx] = tile[m][tx];
  }
}

// ---------------------------------------------------------------------------
extern "C" void kernel_launch(void* const* d_in, const int* in_sizes, int n_in,
                              void* d_out, int out_size, void* d_ws,
                              size_t ws_size, hipStream_t stream) {
  const float* xyz1    = (const float*)d_in[0];
  const float* xyz2    = (const float*)d_in[1];
  const float* points1 = (const float*)d_in[2];
  const float* points2 = (const float*)d_in[3];
  const float* W1  = (const float*)d_in[4];
  const float* b1  = (const float*)d_in[5];
  const float* g1  = (const float*)d_in[6];
  const float* bt1 = (const float*)d_in[7];
  const float* W2  = (const float*)d_in[8];
  const float* b2  = (const float*)d_in[9];
  const float* g2  = (const float*)d_in[10];
  const float* bt2 = (const float*)d_in[11];
  float* out = (float*)d_out;
  char* cur = (char*)d_ws;
  auto alloc = [&](size_t bytes) { char* p = cur; cur += (bytes + 255) & ~255ull; return p; };

  ushort* p2tb = (ushort*)alloc((size_t)B_ * S_ * D2_ * 2);   // [B][S][256]
  ushort* p1tb = (ushort*)alloc((size_t)B_ * N_ * D1_ * 2);   // [B][N][64]
  float*  pd   = (float*)alloc((size_t)B_ * N_ * CH_ * 3 * 4);
  int*    pi   = (int*)alloc((size_t)B_ * N_ * CH_ * 3 * 4);
  int*    idxb = (int*)alloc((size_t)B_ * N_ * 3 * 4);
  float*  wb   = (float*)alloc((size_t)B_ * N_ * 3 * 4);
  ushort* W1b  = (ushort*)alloc((size_t)H_ * CIN_ * 2);
  ushort* W2b  = (ushort*)alloc((size_t)H_ * H_ * 2);
  ushort* xct  = (ushort*)alloc((size_t)B_ * N_ * CIN_ * 2);  // [B][N][320]
  ushort* h1t  = (ushort*)alloc((size_t)B_ * N_ * H_ * 2);    // [B][N][256]
  float*  ps1  = (float*)alloc((size_t)P_ * H_ * 4);
  float*  ps2  = (float*)alloc((size_t)P_ * H_ * 4);
  float*  sc1  = (float*)alloc(H_ * 4);
  float*  sh1  = (float*)alloc(H_ * 4);
  float*  sc2  = (float*)alloc(H_ * 4);
  float*  sh2  = (float*)alloc(H_ * 4);
  ushort* h2b  = xct;   // overlay: xct dead after gemm1

  dim3 blk32(32, 8);

  f2bf_kernel<<<(H_ * CIN_ + 255) / 256, 256, 0, stream>>>(W1, W1b, H_ * CIN_);
  f2bf_kernel<<<(H_ * H_ + 255) / 256, 256, 0, stream>>>(W2, W2b, H_ * H_);

  // points2 [B][256][S] -> p2tb [B][S][256] bf16
  transpose_bf<<<dim3(S_ / 32, D2_ / 32, B_), blk32, 0, stream>>>(
      points2, p2tb, D2_, S_, (size_t)D2_ * S_, (size_t)S_ * D2_);
  // points1 [B][64][N] -> p1tb [B][N][64] bf16
  transpose_bf<<<dim3(N_ / 32, D1_ / 32, B_), blk32, 0, stream>>>(
      points1, p1tb, D1_, N_, (size_t)D1_ * N_, (size_t)N_ * D1_);

  knn3_part<<<dim3(N_ / 256, CH_, B_), 256, 0, stream>>>(xyz1, xyz2, pd, pi);
  knn3_merge<<<dim3(B_ * N_ / 256), 256, 0, stream>>>(pd, pi, idxb, wb);

  build_xct<<<dim3(N_ / 64, B_), 256, 0, stream>>>(p1tb, p2tb, idxb, wb, xct);

  // layer 1: h1t = W1 @ x + b1 (pre-BN bf16, [b][n][m]) + stats
  gemm_fused<CIN_, false><<<dim3(N_ / 128, H_ / 128, B_), 256, 0, stream>>>(
      W1b, xct, b1, nullptr, nullptr, h1t, ps1, ps2);
  bn_stats_fin<<<1, 256, 0, stream>>>(ps1, ps2, g1, bt1, sc1, sh1);

  // layer 2: h2b = W2 @ bnrelu(h1t) + b2 (pre-BN bf16) + stats
  gemm_fused<H_, true><<<dim3(N_ / 128, H_ / 128, B_), 256, 0, stream>>>(
      W2b, h1t, b2, sc1, sh1, h2b, ps1, ps2);
  bn_stats_fin<<<1, 256, 0, stream>>>(ps1, ps2, g2, bt2, sc2, sh2);

  // final BN+ReLU + transpose to d_out [b][m][n] fp32
  bn_out_t<<<dim3(N_ / 32, H_ / 32, B_), blk32, 0, stream>>>(h2b, sc2, sh2, out);
}